// Round 9
// baseline (237.435 us; speedup 1.0000x reference)
//
#include <hip/hip_runtime.h>
#include <hip/hip_bf16.h>
#include <math.h>

#define B_ 4
#define T_ 2048
#define DM 768
#define H_ 12
#define DH 64

typedef __attribute__((ext_vector_type(4))) float f32x4;
typedef __attribute__((ext_vector_type(8))) short s16x8;

typedef const __attribute__((address_space(1))) void* gas1_t;
typedef __attribute__((address_space(3))) void* las3_t;

__device__ __forceinline__ ushort f2b(float f) {
  union { float f; unsigned u; } v; v.f = f;
  unsigned u = v.u;
  u += 0x7fffu + ((u >> 16) & 1u);
  return (ushort)(u >> 16);
}
__device__ __forceinline__ float b2f(ushort b) {
  union { unsigned u; float f; } v; v.u = ((unsigned)b) << 16;
  return v.f;
}

// ---------------- fused prep: x->bf16, 4 weights->bf16, cos/sin pack ----------
// seg0: x 1,572,864 float4 | seg1: weights 589,824 float4 | seg2: cs 16,384 f4
__global__ __launch_bounds__(256) void prep(
    const float* __restrict__ x, const float* __restrict__ wq,
    const float* __restrict__ wk, const float* __restrict__ wv,
    const float* __restrict__ wo, const float* __restrict__ rc,
    const float* __restrict__ rs,
    ushort* __restrict__ xb, ushort* __restrict__ wqkv,
    ushort* __restrict__ wob, float2* __restrict__ cs2) {
  int i = blockIdx.x * 256 + threadIdx.x;
  if (i < 1572864) {
    float4 v = ((const float4*)x)[i];
    ushort4 o;
    o.x = f2b(v.x); o.y = f2b(v.y); o.z = f2b(v.z); o.w = f2b(v.w);
    ((ushort4*)xb)[i] = o;
  } else if (i < 2162688) {
    int i2 = i - 1572864;
    int which = i2 / 147456, j = i2 - which * 147456;
    const float* src = which == 0 ? wq : which == 1 ? wk : which == 2 ? wv : wo;
    ushort* dst = which < 3 ? wqkv + (size_t)which * 589824 : wob;
    float4 v = ((const float4*)src)[j];
    ushort4 o;
    o.x = f2b(v.x); o.y = f2b(v.y); o.z = f2b(v.z); o.w = f2b(v.w);
    ((ushort4*)dst)[j] = o;
  } else if (i < 2179072) {
    int j = i - 2162688;  // 16384 float4s over T_*32=65536 floats
    float4 c = ((const float4*)rc)[j];
    float4 s = ((const float4*)rs)[j];
    float4 o0, o1;
    o0.x = c.x; o0.y = s.x; o0.z = c.y; o0.w = s.y;
    o1.x = c.z; o1.y = s.z; o1.z = c.w; o1.w = s.w;
    ((float4*)cs2)[j * 2] = o0;
    ((float4*)cs2)[j * 2 + 1] = o1;
  }
}

// ---------------- QKV GEMM, BK=64, fused RoPE + scatter epilogue -------------
// LDS rows are 128B (row-bank-invariant); XOR swizzle cb^(row&7) spreads the
// 8 16B-groups so b128 frag reads hit the 8-cycle BW floor. 12 K-iters.
__global__ __launch_bounds__(256) void gemm_qkv(
    const ushort* __restrict__ A, const ushort* __restrict__ Bw,
    const float2* __restrict__ cs2,
    ushort* __restrict__ Qb, ushort* __restrict__ Kb, ushort* __restrict__ Vt) {
  const int K = 768;
  __shared__ ushort As[128 * 64];
  __shared__ ushort Bs[128 * 64];
  const int m0 = blockIdx.y * 128, n0 = blockIdx.x * 128;
  const int tid = threadIdx.x;
  const int wave = tid >> 6, lane = tid & 63;
  const int wm = (wave >> 1) * 64, wn = (wave & 1) * 64;
  const int quad = lane >> 4, l16 = lane & 15;
  const int tr8 = tid >> 3;                      // staging row 0..31 (+32j)
  const int scb = (tid & 7) ^ (tr8 & 7);         // swizzled source colblock
  const int fsw = l16 & 7;                       // frag-read swizzle term

  f32x4 acc[4][4] = {};

  const ushort* ga = A + (size_t)(m0 + tr8) * K + scb * 8;
  const ushort* gb = Bw + (size_t)(n0 + tr8) * K + scb * 8;

  for (int k0 = 0; k0 < K; k0 += 64) {
#pragma unroll
    for (int j = 0; j < 4; j++) {
      __builtin_amdgcn_global_load_lds((gas1_t)(ga + (size_t)j * 32 * K + k0),
                                       (las3_t)(As + j * 2048 + tid * 8), 16, 0, 0);
      __builtin_amdgcn_global_load_lds((gas1_t)(gb + (size_t)j * 32 * K + k0),
                                       (las3_t)(Bs + j * 2048 + tid * 8), 16, 0, 0);
    }
    __syncthreads();
#pragma unroll
    for (int h = 0; h < 2; h++) {
      s16x8 af[4], bf[4];
#pragma unroll
      for (int i = 0; i < 4; i++)
        af[i] = *(const s16x8*)(As + (wm + i * 16 + l16) * 64 + (((h * 4 + quad) ^ fsw) * 8));
#pragma unroll
      for (int n = 0; n < 4; n++)
        bf[n] = *(const s16x8*)(Bs + (wn + n * 16 + l16) * 64 + (((h * 4 + quad) ^ fsw) * 8));
#pragma unroll
      for (int i = 0; i < 4; i++)
#pragma unroll
        for (int n = 0; n < 4; n++)
          acc[i][n] = __builtin_amdgcn_mfma_f32_16x16x32_bf16(af[i], bf[n], acc[i][n], 0, 0, 0);
    }
    __syncthreads();
  }

  const int sec = n0 / 768;  // 0=q, 1=k, 2=v (uniform per block)
  if (sec < 2) {
    ushort* dst = sec == 0 ? Qb : Kb;
#pragma unroll
    for (int i = 0; i < 4; i++) {
      int row0 = m0 + wm + i * 16 + quad * 4;
#pragma unroll
      for (int nt = 0; nt < 4; nt++) {
        int col = n0 + wn + nt * 16 + l16;
        int nn = col - sec * 768;
        int h = nn >> 6, d = nn & 63;
        int ip = (d >> 1) & 31;
        float sgn = (d & 1) ? 1.f : -1.f;
#pragma unroll
        for (int r = 0; r < 4; r++) {
          int rrow = row0 + r;
          int t = rrow & (T_ - 1), bb = rrow >> 11;
          float v = acc[i][nt][r];
          float partner = __shfl_xor(v, 1);
          float2 cs = cs2[t * 32 + ip];
          float out = fmaf(v, cs.x, sgn * partner * cs.y);  // identical to R8
          unsigned ob = (unsigned)f2b(out);
          unsigned other = __shfl_xor(ob, 1);
          if (!(l16 & 1))  // even lane: pack (d, d+1), one b32 store
            *(unsigned*)(dst + ((size_t)(bb * H_ + h) * T_ + t) * DH + d) = ob | (other << 16);
        }
      }
    }
  } else {
#pragma unroll
    for (int i = 0; i < 4; i++) {
      int row0 = m0 + wm + i * 16 + quad * 4;
      int t0 = row0 & (T_ - 1), b = row0 >> 11;  // 4 rows share b (aligned)
#pragma unroll
      for (int nt = 0; nt < 4; nt++) {
        int col = n0 + wn + nt * 16 + l16;
        int nn = col - 1536;
        int h = nn >> 6, d = nn & 63;
        ushort4 pk;
        pk.x = f2b(acc[i][nt][0]); pk.y = f2b(acc[i][nt][1]);
        pk.z = f2b(acc[i][nt][2]); pk.w = f2b(acc[i][nt][3]);
        *(ushort4*)(Vt + ((size_t)(b * H_ + h) * DH + d) * T_ + t0) = pk;
      }
    }
  }
}

// ---------------- output GEMM: 128x64 tiles, BK=64, swizzled LDS -------------
__global__ __launch_bounds__(256) void gemm_out(
    const ushort* __restrict__ A, const ushort* __restrict__ Bw, float* __restrict__ C) {
  const int K = 768, N = 768;
  __shared__ ushort As[128 * 64];
  __shared__ ushort Bs[64 * 64];
  const int m0 = blockIdx.y * 128, n0 = blockIdx.x * 64;
  const int tid = threadIdx.x;
  const int wave = tid >> 6, lane = tid & 63;
  const int wm = wave * 32;
  const int quad = lane >> 4, l16 = lane & 15;
  const int tr8 = tid >> 3;
  const int scb = (tid & 7) ^ (tr8 & 7);
  const int fsw = l16 & 7;

  f32x4 acc[2][4] = {};

  const ushort* ga = A + (size_t)(m0 + tr8) * K + scb * 8;
  const ushort* gb = Bw + (size_t)(n0 + tr8) * K + scb * 8;

  for (int k0 = 0; k0 < K; k0 += 64) {
#pragma unroll
    for (int j = 0; j < 4; j++)
      __builtin_amdgcn_global_load_lds((gas1_t)(ga + (size_t)j * 32 * K + k0),
                                       (las3_t)(As + j * 2048 + tid * 8), 16, 0, 0);
#pragma unroll
    for (int j = 0; j < 2; j++)
      __builtin_amdgcn_global_load_lds((gas1_t)(gb + (size_t)j * 32 * K + k0),
                                       (las3_t)(Bs + j * 2048 + tid * 8), 16, 0, 0);
    __syncthreads();
#pragma unroll
    for (int h = 0; h < 2; h++) {
      s16x8 af[2], bf[4];
#pragma unroll
      for (int i = 0; i < 2; i++)
        af[i] = *(const s16x8*)(As + (wm + i * 16 + l16) * 64 + (((h * 4 + quad) ^ fsw) * 8));
#pragma unroll
      for (int n = 0; n < 4; n++)
        bf[n] = *(const s16x8*)(Bs + (n * 16 + l16) * 64 + (((h * 4 + quad) ^ fsw) * 8));
#pragma unroll
      for (int i = 0; i < 2; i++)
#pragma unroll
        for (int n = 0; n < 4; n++)
          acc[i][n] = __builtin_amdgcn_mfma_f32_16x16x32_bf16(af[i], bf[n], acc[i][n], 0, 0, 0);
    }
    __syncthreads();
  }

#pragma unroll
  for (int i = 0; i < 2; i++) {
    int row = m0 + wm + i * 16 + quad * 4;
#pragma unroll
    for (int n = 0; n < 4; n++) {
      int col = n0 + n * 16 + l16;
#pragma unroll
      for (int r = 0; r < 4; r++)
        C[(size_t)(row + r) * N + col] = acc[i][n][r];
    }
  }
}

// ---------------- causal flash attention v6: dbuf LDS staging (unchanged) ----
#define EXP2SCALE 0.18033688f   /* 0.125 * log2(e) */
#define EXP2OFF  17.312340f     /* 12 * log2(e) */
__global__ __launch_bounds__(256, 3) void attn(const ushort* __restrict__ Qb, const ushort* __restrict__ Kb,
                                               const ushort* __restrict__ Vt, ushort* __restrict__ Ob) {
  const int bh = blockIdx.x;
  const int qt = 15 - blockIdx.y;  // biggest tiles dispatch first
  const int tid = threadIdx.x, wave = tid >> 6, lane = tid & 63;
  const int quad = lane >> 4, l16 = lane & 15;
  const int b = bh / H_, h = bh % H_;
  const ushort* Qp = Qb + (size_t)bh * T_ * DH;
  const ushort* Kp = Kb + (size_t)bh * T_ * DH;
  const ushort* Vp = Vt + (size_t)bh * DH * T_;

  __shared__ ushort Ks[2][64 * 64];
  __shared__ ushort Vs[2][64 * 64];
  __shared__ ushort P[4][16][72];   // per wave, shared across m-frags

  const int qbase0 = qt * 128 + wave * 32;

  s16x8 aq[2][2];
#pragma unroll
  for (int m = 0; m < 2; m++) {
    const ushort* qp = Qp + (size_t)(qbase0 + m * 16 + l16) * DH + quad * 8;
    aq[m][0] = *(const s16x8*)qp;
    aq[m][1] = *(const s16x8*)(qp + 32);
  }
  f32x4 o[2][4] = {};
  float rsum[2][4] = {{0.f, 0.f, 0.f, 0.f}, {0.f, 0.f, 0.f, 0.f}};

  const int ntile = 2 * qt + 2;
  const int srow = tid >> 3;                   // 0..31
  const int scbK = (tid & 7) ^ (srow & 7);     // swizzled source colblock
  const int swz = (l16 & 7);

  {
    const int kv0 = 0;
    __builtin_amdgcn_global_load_lds((gas1_t)(Kp + (size_t)(kv0 + srow) * DH + scbK * 8),
                                     (las3_t)(Ks[0] + tid * 8), 16, 0, 0);
    __builtin_amdgcn_global_load_lds((gas1_t)(Kp + (size_t)(kv0 + srow + 32) * DH + scbK * 8),
                                     (las3_t)(Ks[0] + 2048 + tid * 8), 16, 0, 0);
    __builtin_amdgcn_global_load_lds((gas1_t)(Vp + (size_t)srow * T_ + kv0 + scbK * 8),
                                     (las3_t)(Vs[0] + tid * 8), 16, 0, 0);
    __builtin_amdgcn_global_load_lds((gas1_t)(Vp + (size_t)(srow + 32) * T_ + kv0 + scbK * 8),
                                     (las3_t)(Vs[0] + 2048 + tid * 8), 16, 0, 0);
  }

  for (int c = 0; c < ntile; c++) {
    const int kv0 = c * 64;
    const int cur = c & 1;
    __syncthreads();  // drains own vmcnt -> buf[cur] staged & visible
    if (c + 1 < ntile) {
      const int kv1 = kv0 + 64, nxt = cur ^ 1;
      __builtin_amdgcn_global_load_lds((gas1_t)(Kp + (size_t)(kv1 + srow) * DH + scbK * 8),
                                       (las3_t)(Ks[nxt] + tid * 8), 16, 0, 0);
      __builtin_amdgcn_global_load_lds((gas1_t)(Kp + (size_t)(kv1 + srow + 32) * DH + scbK * 8),
                                       (las3_t)(Ks[nxt] + 2048 + tid * 8), 16, 0, 0);
      __builtin_amdgcn_global_load_lds((gas1_t)(Vp + (size_t)srow * T_ + kv1 + scbK * 8),
                                       (las3_t)(Vs[nxt] + tid * 8), 16, 0, 0);
      __builtin_amdgcn_global_load_lds((gas1_t)(Vp + (size_t)(srow + 32) * T_ + kv1 + scbK * 8),
                                       (las3_t)(Vs[nxt] + 2048 + tid * 8), 16, 0, 0);
    }

    s16x8 kf[4][2];
#pragma unroll
    for (int nt = 0; nt < 4; nt++) {
      const ushort* kr = Ks[cur] + (nt * 16 + l16) * 64;
      kf[nt][0] = *(const s16x8*)(kr + ((quad ^ swz) * 8));
      kf[nt][1] = *(const s16x8*)(kr + (((4 + quad) ^ swz) * 8));
    }
    s16x8 bv[4][2];
#pragma unroll
    for (int dt = 0; dt < 4; dt++) {
      const ushort* vr = Vs[cur] + (dt * 16 + l16) * 64;
      bv[dt][0] = *(const s16x8*)(vr + ((quad ^ swz) * 8));
      bv[dt][1] = *(const s16x8*)(vr + (((4 + quad) ^ swz) * 8));
    }

#pragma unroll
    for (int m = 0; m < 2; m++) {
      const int qb = qbase0 + m * 16;
      if (kv0 > qb + 15) continue;  // fully masked frag (wave-uniform)
      f32x4 s[4] = {};
#pragma unroll
      for (int nt = 0; nt < 4; nt++) {
        s[nt] = __builtin_amdgcn_mfma_f32_16x16x32_bf16(aq[m][0], kf[nt][0], s[nt], 0, 0, 0);
        s[nt] = __builtin_amdgcn_mfma_f32_16x16x32_bf16(aq[m][1], kf[nt][1], s[nt], 0, 0, 0);
      }
      if (kv0 + 63 <= qb) {  // fully unmasked
#pragma unroll
        for (int nt = 0; nt < 4; nt++)
#pragma unroll
          for (int r = 0; r < 4; r++) {
            float p = __builtin_amdgcn_exp2f(fmaf(s[nt][r], EXP2SCALE, -EXP2OFF));
            rsum[m][r] += p;
            P[wave][quad * 4 + r][nt * 16 + l16] = f2b(p);
          }
      } else {  // diagonal tile
#pragma unroll
        for (int nt = 0; nt < 4; nt++) {
          int kv = kv0 + nt * 16 + l16;
#pragma unroll
          for (int r = 0; r < 4; r++) {
            int qi = qb + quad * 4 + r;
            float p = (kv <= qi) ? __builtin_amdgcn_exp2f(fmaf(s[nt][r], EXP2SCALE, -EXP2OFF)) : 0.f;
            rsum[m][r] += p;
            P[wave][quad * 4 + r][nt * 16 + l16] = f2b(p);
          }
        }
      }
      s16x8 ap0 = *(const s16x8*)&P[wave][l16][quad * 8];
      s16x8 ap1 = *(const s16x8*)&P[wave][l16][32 + quad * 8];
#pragma unroll
      for (int dt = 0; dt < 4; dt++) {
        o[m][dt] = __builtin_amdgcn_mfma_f32_16x16x32_bf16(ap0, bv[dt][0], o[m][dt], 0, 0, 0);
        o[m][dt] = __builtin_amdgcn_mfma_f32_16x16x32_bf16(ap1, bv[dt][1], o[m][dt], 0, 0, 0);
      }
    }
  }
#pragma unroll
  for (int off = 1; off < 16; off <<= 1)
#pragma unroll
    for (int m = 0; m < 2; m++)
#pragma unroll
      for (int r = 0; r < 4; r++)
        rsum[m][r] += __shfl_xor(rsum[m][r], off);
#pragma unroll
  for (int m = 0; m < 2; m++)
#pragma unroll
    for (int dt = 0; dt < 4; dt++)
#pragma unroll
      for (int r = 0; r < 4; r++) {
        int q = qbase0 + m * 16 + quad * 4 + r;
        Ob[(size_t)(b * T_ + q) * DM + h * 64 + dt * 16 + l16] = f2b(o[m][dt][r] / rsum[m][r]);
      }
}

extern "C" void kernel_launch(void* const* d_in, const int* in_sizes, int n_in,
                              void* d_out, int out_size, void* d_ws, size_t ws_size,
                              hipStream_t stream) {
  const float* x = (const float*)d_in[0];
  const float* rc = (const float*)d_in[1];
  const float* rs = (const float*)d_in[2];
  const float* wq = (const float*)d_in[3];
  const float* wk = (const float*)d_in[4];
  const float* wv = (const float*)d_in[5];
  const float* wo = (const float*)d_in[6];

  char* ws = (char*)d_ws;
  ushort* xb   = (ushort*)(ws);                 // 12,582,912
  ushort* wqkv = (ushort*)(ws + 12582912);      //  3,538,944
  ushort* wob  = (ushort*)(ws + 16121856);      //  1,179,648
  float2* cs2  = (float2*)(ws + 17301504);      //    524,288
  ushort* Qb   = (ushort*)(ws + 17825792);      // 12,582,912
  ushort* Kb   = (ushort*)(ws + 30408704);      // 12,582,912
  ushort* Vt   = (ushort*)(ws + 42991616);      // 12,582,912
  ushort* Ob   = (ushort*)(ws + 55574528);      // 12,582,912 (ends ~68.2MB)

  prep<<<8512, 256, 0, stream>>>(x, wq, wk, wv, wo, rc, rs, xb, wqkv, wob, cs2);

  gemm_qkv<<<dim3(18, 64), 256, 0, stream>>>(xb, wqkv, cs2, Qb, Kb, Vt);

  attn<<<dim3(48, 16), 256, 0, stream>>>(Qb, Kb, Vt, Ob);

  gemm_out<<<dim3(12, 64), 256, 0, stream>>>(Ob, wob, (float*)d_out);
}